// Round 2
// baseline (100.766 us; speedup 1.0000x reference)
//
#include <hip/hip_runtime.h>

#define B_      16
#define S_      65
#define R_      1040
#define W_      256
#define T_      2176
#define D_      128
#define MAXSEQ  2048

// ---------------------------------------------------------------------------
// Kernel 1 (1 block, 256 thr): fully parallel setup.
//  - per-batch segment-offset scan: one wave per batch, __shfl_up scan (65=64+1)
//  - per-row masked count (exact IEEE fp32 div predicate, matches jax ref)
//  - block-wide exclusive scan of counts (5 rows/thread)
//  - emit lut[g] = (off<<19) | (r<<8) | w  for every compacted slot g
// ---------------------------------------------------------------------------
__global__ __launch_bounds__(256) void interp_setup(
    const float* __restrict__ scales,
    const int*   __restrict__ len_seq,
    const int*   __restrict__ len_seg_raw,
    int* __restrict__ lut,        // [R_*W_] packed (off,r,w) per compact slot
    int* __restrict__ meta)       // [2] total, L
{
    __shared__ int s_len[R_];
    __shared__ int s_off[R_];
    __shared__ int s_wtot[4];
    const int tid  = threadIdx.x;
    const int lane = tid & 63;
    const int wid  = tid >> 6;

    for (int r = tid; r < R_; r += 256) s_len[r] = len_seg_raw[r] + 32; // +MIN_LEN_SEG
    __syncthreads();

    // per-batch exclusive cumsum of 65 segment lengths; one wave per batch
    for (int b = wid; b < B_; b += 4) {
        int v = s_len[b * S_ + lane];            // lanes 0..63 -> elems 0..63
        int incl = v;
        #pragma unroll
        for (int d = 1; d < 64; d <<= 1) {
            int n = __shfl_up(incl, d, 64);
            if (lane >= d) incl += n;
        }
        s_off[b * S_ + lane] = incl - v;         // exclusive prefix
        int tot = __shfl(incl, 63, 64);
        if (lane == 0) s_off[b * S_ + 64] = tot; // element 64
    }
    __syncthreads();

    // per-row masked count: #{ w in [0,256) : fp32(w/sc) < K }
    int c[5], off5[5];
    const int r0 = tid * 5;
    int tsum = 0;
    #pragma unroll
    for (int i = 0; i < 5; ++i) {
        int r = r0 + i, cc = 0, off = 0;
        if (r < R_) {
            float sc = scales[r] + 0.5f;
            off = s_off[r];
            int K = min(s_len[r] - 1, len_seq[r / S_] - 1 - off);
            if (K > 0) {
                cc = (int)ceilf((float)K * sc);
                cc = min(max(cc, 0), W_);
                const float Kf = (float)K;
                while (cc > 0  && ((float)(cc - 1) / sc) >= Kf) --cc; // exact IEEE div
                while (cc < W_ && ((float)cc       / sc) <  Kf) ++cc;
            }
        }
        c[i] = cc; off5[i] = off; tsum += cc;
    }

    // block exclusive scan of per-thread sums
    int incl = tsum;
    #pragma unroll
    for (int d = 1; d < 64; d <<= 1) {
        int n = __shfl_up(incl, d, 64);
        if (lane >= d) incl += n;
    }
    if (lane == 63) s_wtot[wid] = incl;
    __syncthreads();
    int wpre = 0, total = 0;
    #pragma unroll
    for (int wv = 0; wv < 4; ++wv) {
        int t_ = s_wtot[wv];
        if (wv < wid) wpre += t_;
        total += t_;
    }
    int base = wpre + incl - tsum;               // exclusive prefix for this thread

    // emit lut runs
    #pragma unroll
    for (int i = 0; i < 5; ++i) {
        int r = r0 + i;
        if (r < R_) {
            int tag = (off5[i] << 19) | (r << 8);
            for (int w = 0; w < c[i]; ++w) lut[base + w] = tag | w;
            base += c[i];
        }
    }
    if (tid == 0) { meta[0] = total; meta[1] = total / B_; }
}

// ---------------------------------------------------------------------------
// Kernel 2: output-driven gather + lerp. 8 output rows / 256-thr block,
// 32 lanes per row (float4 over D=128). One lut load replaces binary search.
// ---------------------------------------------------------------------------
__global__ __launch_bounds__(256) void interp_gather(
    const float* __restrict__ x,
    const float* __restrict__ scales,
    const int*   __restrict__ lut,
    const int*   __restrict__ meta,
    float* __restrict__ out)
{
    __shared__ int s_L;
    if (threadIdx.x == 0) s_L = meta[1];
    __syncthreads();
    const int L = s_L;

    const int tid  = threadIdx.x;
    const int orow = blockIdx.x * 8 + (tid >> 5);   // [0, 32768)
    const int lane = tid & 31;
    float4* outp = (float4*)(out + (size_t)orow * D_) + lane;

    const int t = orow & (MAXSEQ - 1);
    const int b = orow >> 11;
    if (t >= L) { *outp = make_float4(0.f, 0.f, 0.f, 0.f); return; }

    const int v   = lut[b * L + t];
    const int w   = v & 255;
    const int r   = (v >> 8) & 2047;
    const int off = v >> 19;

    const float sc  = scales[r] + 0.5f;
    const float is  = (float)w / sc;                // IEEE fp32 div, matches ref
    const float fl  = floorf(is);
    const float lam = is - fl;
    const int i0 = (int)fl + off;                   // in [0, 2046] for masked slots
    const int bs = r / S_;

    const float* base = x + (size_t)bs * (T_ * D_);
    const float4* pa = (const float4*)(base + (size_t)i0 * D_) + lane;
    const float4* pb = (const float4*)(base + (size_t)(i0 + 1) * D_) + lane;
    const float4 a = *pa, cc = *pb;
    const float om = 1.0f - lam;
    float4 y;
    y.x = om * a.x + lam * cc.x;
    y.y = om * a.y + lam * cc.y;
    y.z = om * a.z + lam * cc.z;
    y.w = om * a.w + lam * cc.w;
    *outp = y;
}

extern "C" void kernel_launch(void* const* d_in, const int* in_sizes, int n_in,
                              void* d_out, int out_size, void* d_ws, size_t ws_size,
                              hipStream_t stream) {
    const float* x           = (const float*)d_in[0];  // (16, 2176, 128) f32
    const float* scales      = (const float*)d_in[1];  // (1040,) f32
    const int*   len_seq     = (const int*)d_in[2];    // (16,) i32
    const int*   len_seg_raw = (const int*)d_in[3];    // (1040,1) i32
    float*       out         = (float*)d_out;          // (16, 2048, 128) f32

    int* lut  = (int*)d_ws;            // R_*W_ ints (1 MiB)
    int* meta = lut + R_ * W_;         // 2 ints

    interp_setup<<<1, 256, 0, stream>>>(scales, len_seq, len_seg_raw, lut, meta);

    const int nrows = B_ * MAXSEQ;     // 32768 output rows
    interp_gather<<<nrows / 8, 256, 0, stream>>>(x, scales, lut, meta, out);
}

// Round 3
// 87.265 us; speedup vs baseline: 1.1547x; 1.1547x over previous
//
#include <hip/hip_runtime.h>

#define B_      16
#define S_      65
#define R_      1040
#define W_      256
#define T_      2176
#define D_      128
#define MAXSEQ  2048

// ---------------------------------------------------------------------------
// Kernel 1 (1 block, 256 thr): fully parallel setup, NO lut emission.
//  - per-batch segment-offset scan: one wave per batch, __shfl_up scan
//  - per-row masked count (exact IEEE fp32 div predicate, matches jax ref)
//  - block-wide exclusive scan of counts (5 rows/thread) -> row_start[1041]
// ---------------------------------------------------------------------------
__global__ __launch_bounds__(256) void interp_setup(
    const float* __restrict__ scales,
    const int*   __restrict__ len_seq,
    const int*   __restrict__ len_seg_raw,
    int* __restrict__ offs,        // [R_] per-row source offset
    int* __restrict__ row_start,   // [R_+1] exclusive scan of counts
    int* __restrict__ meta)        // [2] total, L
{
    __shared__ int s_len[R_];
    __shared__ int s_off[R_];
    __shared__ int s_wtot[4];
    const int tid  = threadIdx.x;
    const int lane = tid & 63;
    const int wid  = tid >> 6;

    for (int r = tid; r < R_; r += 256) s_len[r] = len_seg_raw[r] + 32; // +MIN_LEN_SEG
    __syncthreads();

    // per-batch exclusive cumsum of 65 segment lengths; one wave per batch
    for (int b = wid; b < B_; b += 4) {
        int v = s_len[b * S_ + lane];            // lanes 0..63 -> segs 0..63
        int incl = v;
        #pragma unroll
        for (int d = 1; d < 64; d <<= 1) {
            int n = __shfl_up(incl, d, 64);
            if (lane >= d) incl += n;
        }
        s_off[b * S_ + lane] = incl - v;         // exclusive prefix
        int tot = __shfl(incl, 63, 64);
        if (lane == 0) s_off[b * S_ + 64] = tot; // seg 64's exclusive prefix
    }
    __syncthreads();

    // per-row masked count: #{ w in [0,256) : fp32(w/sc) < K }
    int c[5];
    const int r0 = tid * 5;
    int tsum = 0;
    #pragma unroll
    for (int i = 0; i < 5; ++i) {
        int r = r0 + i, cc = 0;
        if (r < R_) {
            float sc = scales[r] + 0.5f;
            int off = s_off[r];
            int K = min(s_len[r] - 1, len_seq[r / S_] - 1 - off);
            if (K > 0) {
                cc = (int)ceilf((float)K * sc);
                cc = min(max(cc, 0), W_);
                const float Kf = (float)K;
                while (cc > 0  && ((float)(cc - 1) / sc) >= Kf) --cc; // exact IEEE div
                while (cc < W_ && ((float)cc       / sc) <  Kf) ++cc;
            }
            offs[r] = off;
        }
        c[i] = cc; tsum += cc;
    }

    // block exclusive scan of per-thread sums
    int incl = tsum;
    #pragma unroll
    for (int d = 1; d < 64; d <<= 1) {
        int n = __shfl_up(incl, d, 64);
        if (lane >= d) incl += n;
    }
    if (lane == 63) s_wtot[wid] = incl;
    __syncthreads();
    int wpre = 0, total = 0;
    #pragma unroll
    for (int wv = 0; wv < 4; ++wv) {
        int t_ = s_wtot[wv];
        if (wv < wid) wpre += t_;
        total += t_;
    }
    int base = wpre + incl - tsum;               // exclusive prefix for this thread

    #pragma unroll
    for (int i = 0; i < 5; ++i) {
        int r = r0 + i;
        if (r < R_) { row_start[r] = base; base += c[i]; }
    }
    if (tid == 0) {
        row_start[R_] = total;
        meta[0] = total;
        meta[1] = total / B_;
    }
}

// ---------------------------------------------------------------------------
// Kernel 2: output-driven gather + lerp. 8 output rows / 256-thr block,
// 32 lanes per row (float4 over D=128). Binary search of row_start in LDS.
// ---------------------------------------------------------------------------
__global__ __launch_bounds__(256) void interp_gather(
    const float* __restrict__ x,
    const float* __restrict__ scales,
    const int*   __restrict__ offs,
    const int*   __restrict__ row_start,
    const int*   __restrict__ meta,
    float* __restrict__ out)
{
    __shared__ int s_rs[R_ + 1];
    __shared__ int s_of[R_];
    const int tid = threadIdx.x;
    for (int i = tid; i < R_ + 1; i += 256) s_rs[i] = row_start[i];
    for (int i = tid; i < R_;     i += 256) s_of[i] = offs[i];
    __syncthreads();

    const int L    = meta[1];
    const int orow = blockIdx.x * 8 + (tid >> 5);   // [0, 32768)
    const int lane = tid & 31;
    float4* outp = (float4*)(out + (size_t)orow * D_) + lane;

    const int t = orow & (MAXSEQ - 1);
    const int b = orow >> 11;
    if (t >= L) { *outp = make_float4(0.f, 0.f, 0.f, 0.f); return; }

    const int g = b * L + t;                        // g < total guaranteed
    // largest r with row_start[r] <= g  (invariant: rs[lo] <= g < rs[hi])
    int lo = 0, hi = R_;
    while (hi - lo > 1) {
        int mid = (lo + hi) >> 1;
        if (s_rs[mid] <= g) lo = mid; else hi = mid;
    }
    const int r = lo;
    const int w = g - s_rs[r];

    const float sc  = scales[r] + 0.5f;
    const float is  = (float)w / sc;                // IEEE fp32 div, matches ref
    const float fl  = floorf(is);
    const float lam = is - fl;
    const int i0 = (int)fl + s_of[r];               // in [0, 2046] for masked slots
    const int bs = r / S_;                          // source batch from segment row

    const float* base = x + (size_t)bs * (T_ * D_);
    const float4* pa = (const float4*)(base + (size_t)i0 * D_) + lane;
    const float4* pb = (const float4*)(base + (size_t)(i0 + 1) * D_) + lane;
    const float4 a = *pa, cc = *pb;
    const float om = 1.0f - lam;
    float4 y;
    y.x = om * a.x + lam * cc.x;
    y.y = om * a.y + lam * cc.y;
    y.z = om * a.z + lam * cc.z;
    y.w = om * a.w + lam * cc.w;
    *outp = y;
}

extern "C" void kernel_launch(void* const* d_in, const int* in_sizes, int n_in,
                              void* d_out, int out_size, void* d_ws, size_t ws_size,
                              hipStream_t stream) {
    const float* x           = (const float*)d_in[0];  // (16, 2176, 128) f32
    const float* scales      = (const float*)d_in[1];  // (1040,) f32
    const int*   len_seq     = (const int*)d_in[2];    // (16,) i32
    const int*   len_seg_raw = (const int*)d_in[3];    // (1040,1) i32
    float*       out         = (float*)d_out;          // (16, 2048, 128) f32

    int* offs      = (int*)d_ws;         // R_
    int* row_start = offs + R_;          // R_+1
    int* meta      = row_start + R_ + 1; // 2

    interp_setup<<<1, 256, 0, stream>>>(scales, len_seq, len_seg_raw,
                                        offs, row_start, meta);

    const int nrows = B_ * MAXSEQ;       // 32768 output rows
    interp_gather<<<nrows / 8, 256, 0, stream>>>(x, scales, offs, row_start,
                                                 meta, out);
}